// Round 6
// baseline (85.511 us; speedup 1.0000x reference)
//
#include <hip/hip_runtime.h>
#include <hip/hip_bf16.h>

// Problem constants
#define NN    32
#define CC    49
#define HWSZ  81
#define MSZ   24
#define KSZ   7
#define PADSZ 3
#define NHW   (NN*HWSZ)     // 2592
#define NCHW  (NN*CC*HWSZ)  // 127008

// LDS strides (in shorts / bf16 elements). All row strides * 2B are multiples
// of 16B (b128-aligned fragment loads) and chosen to stagger bank starts.
// Total LDS = 13312 + 13312 + 13824 + 9216 = 49664 B < 52 KB -> 3 blocks/CU.
#define XSB_S  104   // xsb[64][104]  : x[n] as bf16 (FULLY zero-filled: pad NaN-safe)
#define MSK_S  104   // msk[64][104]  : mask rows dd (FULLY zero-filled)
#define MSKT_S 72    // mskT[96][72]  : mask transposed (FULLY zero-filled)
#define G_S    72    // gm[64][72]    : leaky(fk)[c][dd] (fully overwritten - no fill)

typedef __attribute__((ext_vector_type(8))) short short8;
typedef __attribute__((ext_vector_type(4))) short short4v;
typedef __attribute__((ext_vector_type(4))) float f32x4;

__device__ __forceinline__ short f2b(float v) {
    unsigned u = __float_as_uint(v);
    u += 0x7fffu + ((u >> 16) & 1u);      // round-to-nearest-even to bf16
    return (short)(u >> 16);
}
__device__ __forceinline__ float b2f(short s) {
    return __uint_as_float(((unsigned)(unsigned short)s) << 16);
}

// Kernel 1: one block (256 thr = 4 waves) per (n, o).
//   phase 0: zero-fill xsb/msk/mskT; BARRIER
//   phase 1a: stage x->xsb(bf16); BARRIER (conv now reads xsb from LDS)
//   phase 1b: conv(K=7 over channel)+softmax(81), 4 rows/wave, 16-lane shuffles
//   phase 2: MFMA  fkT[dd][c] = msk(64x96) . xsb^T -> leaky -> gm[c][dd]
//   phase 3: MFMA  out_partial[c][hw] = gm(64x64) . mskT^T -> stores to ws
// NaN-safety: every LDS word an MFMA reads is either real data or explicit 0.
__global__ __launch_bounds__(256) void fuse_k1(
    const float* __restrict__ x, const float* __restrict__ cw,
    const float* __restrict__ cb, float* __restrict__ acc,
    float* __restrict__ stats, int use_ws)
{
    __shared__ short xsb [64 * XSB_S];    // 13312 B
    __shared__ short msk [64 * MSK_S];    // 13312 B
    __shared__ short mskT[96 * MSKT_S];   // 13824 B
    __shared__ short gm  [64 * G_S];      //  9216 B

    const int o = blockIdx.x;          // 0..23
    const int n = blockIdx.y;          // 0..31
    const int t = threadIdx.x;
    const int lane = t & 63;
    const int wv = t >> 6;             // 0..3
    const int lr = lane & 15;
    const int lq = lane >> 4;          // quad index 0..3

    // block (0,0) zeroes the BN stats accumulators (read only by fuse_k2a,
    // which is stream-ordered after this kernel completes).
    if (use_ws && o == 0 && n == 0 && t < 98) stats[t] = 0.f;

    // ---- phase 0: zero-fill all MFMA-read LDS (16B per store)
    {
        f32x4 z = {0.f, 0.f, 0.f, 0.f};
        for (int i = t; i < 832; i += 256) {        // 6656 shorts each
            ((f32x4*)xsb)[i] = z;
            ((f32x4*)msk)[i] = z;
        }
        for (int i = t; i < 864; i += 256)          // 6912 shorts
            ((f32x4*)mskT)[i] = z;
    }

    const float* xg = x + (size_t)n * CC * HWSZ;
    float wk[KSZ];
    #pragma unroll
    for (int k = 0; k < KSZ; ++k) wk[k] = cw[o * KSZ + k];
    const float bias = cb[o];
    __syncthreads();   // zero-fill complete before staging overwrites data cols

    // ---- phase 1a: stage x[n] into xsb (bf16, row-major [c][hw])
    for (int i = t; i < CC * HWSZ; i += 256) {
        int c = i / HWSZ, hw = i - c * HWSZ;
        xsb[c * XSB_S + hw] = f2b(xg[i]);
    }
    __syncthreads();   // staging complete before conv reads xsb

    // ---- phase 1b: conv + softmax: 4 rows per wave (row = lq), inputs from LDS.
    // Lane lr covers cols lr, lr+16, lr+32, lr+48, lr+64 (+80 on lr==0).
    #pragma unroll
    for (int it = 0; it < 4; ++it) {
        int dd = it * 16 + wv * 4 + lq;
        if (dd < CC) {
            float a0 = 0.f, a1 = 0.f, a2 = 0.f, a3 = 0.f, a4 = 0.f, a5 = 0.f;
            #pragma unroll
            for (int k = 0; k < KSZ; ++k) {
                int r = dd + k - PADSZ;
                if (r >= 0 && r < CC) {
                    const short* xr = xsb + r * XSB_S;
                    float w = wk[k];
                    a0 += w * b2f(xr[lr]);
                    a1 += w * b2f(xr[lr + 16]);
                    a2 += w * b2f(xr[lr + 32]);
                    a3 += w * b2f(xr[lr + 48]);
                    a4 += w * b2f(xr[lr + 64]);
                    if (lr == 0) a5 += w * b2f(xr[80]);
                }
            }
            a0 += bias; a1 += bias; a2 += bias; a3 += bias; a4 += bias;
            a5 = (lr == 0) ? (a5 + bias) : -1e30f;
            float mx = fmaxf(fmaxf(fmaxf(a0, a1), fmaxf(a2, a3)), fmaxf(a4, a5));
            #pragma unroll
            for (int off = 8; off; off >>= 1) mx = fmaxf(mx, __shfl_xor(mx, off, 64));
            float e0 = __expf(a0 - mx), e1 = __expf(a1 - mx), e2 = __expf(a2 - mx);
            float e3 = __expf(a3 - mx), e4 = __expf(a4 - mx);
            float e5 = (lr == 0) ? __expf(a5 - mx) : 0.f;
            float s = e0 + e1 + e2 + e3 + e4 + e5;
            #pragma unroll
            for (int off = 8; off; off >>= 1) s += __shfl_xor(s, off, 64);
            float inv = 1.f / s;
            short b0 = f2b(e0 * inv), b1 = f2b(e1 * inv), b2 = f2b(e2 * inv);
            short b3 = f2b(e3 * inv), b4 = f2b(e4 * inv);
            short* mrow = msk + dd * MSK_S;
            mrow[lr]      = b0;  mskT[(lr     ) * MSKT_S + dd] = b0;
            mrow[lr + 16] = b1;  mskT[(lr + 16) * MSKT_S + dd] = b1;
            mrow[lr + 32] = b2;  mskT[(lr + 32) * MSKT_S + dd] = b2;
            mrow[lr + 48] = b3;  mskT[(lr + 48) * MSKT_S + dd] = b3;
            mrow[lr + 64] = b4;  mskT[(lr + 64) * MSKT_S + dd] = b4;
            if (lr == 0) {
                short b5 = f2b(e5 * inv);
                mrow[80] = b5;   mskT[80 * MSKT_S + dd] = b5;
            }
        }
    }
    __syncthreads();

    // ---- matmul-2 (MFMA): fkT[dd][c] = sum_hw msk[dd][hw] * xsb[c][hw]
    // M=dd (4 tiles, one per wave), N=c (4 tiles), K=hw (96, 3 steps).
    {
        short8 a2[3];
        #pragma unroll
        for (int ks = 0; ks < 3; ++ks)
            a2[ks] = *(const short8*)&msk[(wv * 16 + lr) * MSK_S + ks * 32 + lq * 8];
        #pragma unroll
        for (int nt = 0; nt < 4; ++nt) {
            f32x4 accv = {0.f, 0.f, 0.f, 0.f};
            #pragma unroll
            for (int ks = 0; ks < 3; ++ks) {
                short8 b = *(const short8*)&xsb[(nt * 16 + lr) * XSB_S + ks * 32 + lq * 8];
                accv = __builtin_amdgcn_mfma_f32_16x16x32_bf16(a2[ks], b, accv, 0, 0, 0);
            }
            // C-layout: lane holds fkT[dd = wv*16 + lq*4 + r][c = nt*16 + lr]
            short4v pk;
            #pragma unroll
            for (int r = 0; r < 4; ++r) {
                float v = accv[r];
                v = (v >= 0.f) ? v : 0.01f * v;
                pk[r] = f2b(v);
            }
            *(short4v*)&gm[(nt * 16 + lr) * G_S + wv * 16 + lq * 4] = pk;
        }
    }
    __syncthreads();

    // ---- matmul-1 (MFMA): out_partial[c][hw] = sum_dd gm[c][dd] * mskT[hw][dd]
    // M=c (4 tiles, one per wave), N=hw (6 tiles), K=dd (64, 2 steps).
    {
        float* dstn = use_ws ? (acc + (size_t)(o * NN + n) * CC * HWSZ)
                             : (acc + (size_t)n * CC * HWSZ);
        short8 a1[2];
        #pragma unroll
        for (int ks = 0; ks < 2; ++ks)
            a1[ks] = *(const short8*)&gm[(wv * 16 + lr) * G_S + ks * 32 + lq * 8];
        #pragma unroll
        for (int nt = 0; nt < 6; ++nt) {
            f32x4 accv = {0.f, 0.f, 0.f, 0.f};
            #pragma unroll
            for (int ks = 0; ks < 2; ++ks) {
                short8 b = *(const short8*)&mskT[(nt * 16 + lr) * MSKT_S + ks * 32 + lq * 8];
                accv = __builtin_amdgcn_mfma_f32_16x16x32_bf16(a1[ks], b, accv, 0, 0, 0);
            }
            int hw = nt * 16 + lr;
            if (hw < HWSZ) {
                int cb = wv * 16 + lq * 4;
                if (use_ws) {
                    #pragma unroll
                    for (int r = 0; r < 4; ++r) {
                        int c = cb + r;
                        if (c < CC) dstn[c * HWSZ + hw] = accv[r];
                    }
                } else {
                    #pragma unroll
                    for (int r = 0; r < 4; ++r) {
                        int c = cb + r;
                        if (c < CC) atomicAdd(dstn + c * HWSZ + hw, accv[r]);
                    }
                }
            }
        }
    }
}

// Kernel 2a: grid (49, 4). Block (c, s) handles n in [8s, 8s+8): sums the 24
// per-o partials + residual, writes unnormalized v to out, and atomically
// accumulates (sum, sumsq) into stats[c] / stats[49+c].
__global__ __launch_bounds__(256) void fuse_k2a(
    const float* __restrict__ ws, const float* __restrict__ x,
    float* __restrict__ out, float* __restrict__ stats)
{
    const int c = blockIdx.x;          // 0..48
    const int s = blockIdx.y;          // 0..3
    const int t = threadIdx.x;
    float sum = 0.f, sq = 0.f;
    for (int i = t; i < 8 * HWSZ; i += 256) {     // 648 elems
        int n = 8 * s + i / HWSZ;
        int hw = i - (i / HWSZ) * HWSZ;
        int idx = (n * CC + c) * HWSZ + hw;
        float v = x[idx];
        #pragma unroll
        for (int o = 0; o < MSZ; ++o) v += ws[(size_t)o * NCHW + idx];
        out[idx] = v;
        sum += v; sq += v * v;
    }
    #pragma unroll
    for (int off = 32; off; off >>= 1) {
        sum += __shfl_xor(sum, off, 64);
        sq  += __shfl_xor(sq, off, 64);
    }
    __shared__ float rs[4], rq[4];
    const int lane = t & 63, wv = t >> 6;
    if (lane == 0) { rs[wv] = sum; rq[wv] = sq; }
    __syncthreads();
    if (t == 0) {
        float ts = rs[0] + rs[1] + rs[2] + rs[3];
        float tq = rq[0] + rq[1] + rq[2] + rq[3];
        atomicAdd(&stats[c], ts);
        atomicAdd(&stats[CC + c], tq);
    }
}

// Kernel 2b: normalize out in place using the completed per-channel stats.
__global__ __launch_bounds__(256) void fuse_k2b(
    float* __restrict__ out, const float* __restrict__ stats,
    const float* __restrict__ gamma, const float* __restrict__ beta)
{
    int i = blockIdx.x * 256 + threadIdx.x;
    if (i < NCHW) {
        int c = (i / HWSZ) % CC;
        const float invD = 1.f / (float)NHW;
        float mean = stats[c] * invD;
        float var  = stats[CC + c] * invD - mean * mean;
        float scal = rsqrtf(var + 1e-5f) * gamma[c];
        out[i] = (out[i] - mean) * scal + beta[c];
    }
}

// Kernel 2 (fallback, atomic path): residual add + batch-norm in-place on d_out.
__global__ __launch_bounds__(1024) void fuse_k2(
    float* __restrict__ out, const float* __restrict__ x,
    const float* __restrict__ gamma, const float* __restrict__ beta)
{
    const int c = blockIdx.x;
    const int t = threadIdx.x;
    float vals[3];
    float sum = 0.f, sq = 0.f;
    int cnt = 0;
    for (int i = t; i < NHW; i += 1024) {
        int n = i / HWSZ;
        int hw = i - n * HWSZ;
        int idx = (n * CC + c) * HWSZ + hw;
        float v = out[idx] + x[idx];
        vals[cnt++] = v;
        sum += v; sq += v * v;
    }
    #pragma unroll
    for (int off = 32; off; off >>= 1) {
        sum += __shfl_xor(sum, off, 64);
        sq  += __shfl_xor(sq, off, 64);
    }
    __shared__ float rs[16], rq[16];
    const int lane = t & 63, wv = t >> 6;
    if (lane == 0) { rs[wv] = sum; rq[wv] = sq; }
    __syncthreads();
    float ts = 0.f, tq = 0.f;
    #pragma unroll
    for (int w = 0; w < 16; ++w) { ts += rs[w]; tq += rq[w]; }
    const float invD = 1.f / (float)NHW;
    float mean = ts * invD;
    float var  = tq * invD - mean * mean;
    float scal = rsqrtf(var + 1e-5f) * gamma[c];
    float shft = beta[c] - mean * scal;
    cnt = 0;
    for (int i = t; i < NHW; i += 1024) {
        int n = i / HWSZ;
        int hw = i - n * HWSZ;
        out[(n * CC + c) * HWSZ + hw] = vals[cnt++] * scal + shft;
    }
}

extern "C" void kernel_launch(void* const* d_in, const int* in_sizes, int n_in,
                              void* d_out, int out_size, void* d_ws, size_t ws_size,
                              hipStream_t stream) {
    const float* x     = (const float*)d_in[0];
    const float* cw    = (const float*)d_in[1];
    const float* cb    = (const float*)d_in[2];
    const float* gamma = (const float*)d_in[3];
    const float* beta  = (const float*)d_in[4];
    float* out = (float*)d_out;

    const size_t need = (size_t)MSZ * NCHW * sizeof(float) + 2 * CC * sizeof(float);
    if (ws_size >= need) {
        float* ws    = (float*)d_ws;
        float* stats = ws + (size_t)MSZ * NCHW;     // 98 floats at the tail
        fuse_k1<<<dim3(MSZ, NN), 256, 0, stream>>>(x, cw, cb, ws, stats, 1);
        fuse_k2a<<<dim3(CC, 4), 256, 0, stream>>>(ws, x, out, stats);
        fuse_k2b<<<(NCHW + 255) / 256, 256, 0, stream>>>(out, stats, gamma, beta);
    } else {
        hipMemsetAsync(out, 0, (size_t)NCHW * sizeof(float), stream);
        fuse_k1<<<dim3(MSZ, NN), 256, 0, stream>>>(x, cw, cb, out, nullptr, 0);
        fuse_k2<<<CC, 1024, 0, stream>>>(out, x, gamma, beta);
    }
}